// Round 1
// baseline (183.354 us; speedup 1.0000x reference)
//
#include <hip/hip_runtime.h>
#include <stdint.h>

#define BN            16384
#define PHASE_PTS     4096
#define NPHASE        4
#define BLOCK_THREADS 1024
#define WAVES_PER_BLOCK 16
#define KOUT          16

// float -> sortable uint: ascending uint == ascending float
__device__ __forceinline__ unsigned f2key(float p) {
    unsigned u = __float_as_uint(p);
    return u ^ ((unsigned)((int)u >> 31) | 0x80000000u);
}

__global__ __launch_bounds__(BLOCK_THREADS) void knn_far_kernel(
    const float* __restrict__ x, float* __restrict__ out_d, float* __restrict__ out_i) {
    extern __shared__ float4 buf[];  // PHASE_PTS float4 = 64KB

    const int tid  = threadIdx.x;
    const int lane = tid & 63;
    const int wid  = tid >> 6;
    const int q    = blockIdx.x * WAVES_PER_BLOCK + wid;  // query point index

    // Query point + its squared norm, exact np order: (x0^2 + x1^2) + x2^2
    const float xi0 = x[3 * q], xi1 = x[3 * q + 1], xi2 = x[3 * q + 2];
    const float sqi = __fadd_rn(__fadd_rn(__fmul_rn(xi0, xi0), __fmul_rn(xi1, xi1)),
                                __fmul_rn(xi2, xi2));

    // Distributed sorted list: lane r (r<17) holds rank-r key (smallest pair = farthest first).
    // K = (sortable_t << 32) | j ; ascending K == (pair asc, idx asc) == (dist^2 desc, idx asc)
    uint64_t K = 0xFFFFFFFFFFFFFFFFull;
    unsigned filter_t = 0xFFFFFFFFu;  // t of rank-16 element (wave-uniform)

    for (int ph = 0; ph < NPHASE; ++ph) {
        __syncthreads();
        // ---- stage PHASE_PTS points into LDS as (x, y, z, sq) ----
        const int pbase = ph * PHASE_PTS;
#pragma unroll
        for (int kk = 0; kk < PHASE_PTS / BLOCK_THREADS; ++kk) {
            const int pl = tid + kk * BLOCK_THREADS;
            const int P  = pbase + pl;
            const float gx = x[3 * P], gy = x[3 * P + 1], gz = x[3 * P + 2];
            const float sq = __fadd_rn(__fadd_rn(__fmul_rn(gx, gx), __fmul_rn(gy, gy)),
                                       __fmul_rn(gz, gz));
            buf[pl] = make_float4(gx, gy, gz, sq);
        }
        __syncthreads();

        // ---- scan: 64 candidates per tile, one per lane ----
        for (int tile = 0; tile < PHASE_PTS / 64; ++tile) {
            const float4 c = buf[tile * 64 + lane];
            // dot in BLAS fma-chain order; pair = ((2*dot) - sqi) - sqj, no contraction
            const float dot = __builtin_fmaf(xi2, c.z,
                              __builtin_fmaf(xi1, c.y, __fmul_rn(xi0, c.x)));
            const float p   = __fsub_rn(__fsub_rn(__fmul_rn(2.0f, dot), sqi), c.w);
            const unsigned t = f2key(p);

            uint64_t mask = __ballot(t < filter_t);
            if (mask) {
                const int jbase = pbase + tile * 64;
                do {
                    const int b = __builtin_ctzll(mask);
                    mask &= mask - 1;
                    const unsigned tc = (unsigned)__builtin_amdgcn_readlane((int)t, b);
                    if (tc < filter_t) {  // re-check against tightened filter
                        const uint64_t Kc = ((uint64_t)tc << 32) | (unsigned)(jbase + b);
                        const uint64_t bal = __ballot(Kc < K);
                        const int pos = __builtin_ctzll(bal);  // insertion rank (<=16)
                        const uint64_t Kup = __shfl_up((unsigned long long)K, 1);
                        K = (lane == pos) ? Kc : ((lane > pos) ? Kup : K);
                        filter_t = (unsigned)__builtin_amdgcn_readlane((int)(unsigned)(K >> 32), 16);
                    }
                } while (mask);
            }
        }
    }

    // ---- output ranks 1..16 (rank 0 = farthest overall is dropped by the reference) ----
    if (lane >= 1 && lane <= KOUT) {
        const unsigned tt = (unsigned)(K >> 32);
        const unsigned u  = tt ^ ((unsigned)((int)(~tt) >> 31) | 0x80000000u);  // inverse f2key
        const float pval  = __uint_as_float(u);
        const unsigned j  = (unsigned)(K & 0xFFFFFFFFu);
        out_d[q * KOUT + (lane - 1)] = pval;       // = pair value = -dist^2
        out_i[q * KOUT + (lane - 1)] = (float)j;   // index written as float32
    }
}

extern "C" void kernel_launch(void* const* d_in, const int* in_sizes, int n_in,
                              void* d_out, int out_size, void* d_ws, size_t ws_size,
                              hipStream_t stream) {
    const float* x = (const float*)d_in[0];
    float* out_d = (float*)d_out;            // 8*2048*16 dists
    float* out_i = out_d + (size_t)BN * KOUT;  // 8*2048*16 indices (as float)
    hipLaunchKernelGGL(knn_far_kernel, dim3(BN / WAVES_PER_BLOCK), dim3(BLOCK_THREADS),
                       PHASE_PTS * sizeof(float4), stream, x, out_d, out_i);
}

// Round 2
// 177.248 us; speedup vs baseline: 1.0344x; 1.0344x over previous
//
#include <hip/hip_runtime.h>
#include <stdint.h>

#define BN            16384
#define PHASE_PTS     4096
#define NPHASE        4
#define BLOCK_THREADS 1024
#define KOUT          16
// Q=2 queries per wave: 8192 waves exactly fills 256 CU x 32 wave slots.
// 64KB LDS/block -> 2 blocks/CU (1024 thr each) = full 2048 thr/CU.

// float-bits -> sortable uint (ascending uint == ascending float)
__device__ __forceinline__ unsigned f2key_u(unsigned u) {
    return u ^ ((unsigned)((int)u >> 31) | 0x80000000u);
}
// inverse
__device__ __forceinline__ unsigned key2f_u(unsigned t) {
    return t ^ ((unsigned)((int)(~t) >> 31) | 0x80000000u);
}

__global__ __launch_bounds__(BLOCK_THREADS) void knn_far_kernel(
    const float* __restrict__ x, float* __restrict__ out_d, float* __restrict__ out_i) {
    extern __shared__ float4 buf[];  // PHASE_PTS float4 = 64KB

    const int tid  = threadIdx.x;
    const int lane = tid & 63;
    const int wid  = tid >> 6;
    const int q0   = blockIdx.x * (2 * (BLOCK_THREADS / 64)) + wid * 2;
    const int q1   = q0 + 1;

    // Query points + squared norms, exact np order: (x0^2 + x1^2) + x2^2
    const float a0 = x[3 * q0], a1 = x[3 * q0 + 1], a2 = x[3 * q0 + 2];
    const float b0 = x[3 * q1], b1 = x[3 * q1 + 1], b2 = x[3 * q1 + 2];
    const float sqa = __fadd_rn(__fadd_rn(__fmul_rn(a0, a0), __fmul_rn(a1, a1)), __fmul_rn(a2, a2));
    const float sqb = __fadd_rn(__fadd_rn(__fmul_rn(b0, b0), __fmul_rn(b1, b1)), __fmul_rn(b2, b2));

    // Distributed sorted lists: lane r holds rank-r (key T, idx J). Lanes past the
    // live top-17 trail in sorted order (shifted-out elements, then 0xFFFFFFFF),
    // so the whole 64-lane array is always sorted ascending -> stale candidates
    // self-insert into the junk zone with no re-check needed.
    unsigned T0 = 0xFFFFFFFFu, J0 = 0u;
    unsigned T1 = 0xFFFFFFFFu, J1 = 0u;
    float f0 = __uint_as_float(0x7F800000u);  // +inf until list fills
    float f1 = f0;

    for (int ph = 0; ph < NPHASE; ++ph) {
        __syncthreads();
        const int pbase = ph * PHASE_PTS;
#pragma unroll
        for (int kk = 0; kk < PHASE_PTS / BLOCK_THREADS; ++kk) {
            const int pl = tid + kk * BLOCK_THREADS;
            const int P  = pbase + pl;
            const float gx = x[3 * P], gy = x[3 * P + 1], gz = x[3 * P + 2];
            const float sq = __fadd_rn(__fadd_rn(__fmul_rn(gx, gx), __fmul_rn(gy, gy)),
                                       __fmul_rn(gz, gz));
            buf[pl] = make_float4(gx, gy, gz, sq);
        }
        __syncthreads();

#pragma unroll 4
        for (int tile = 0; tile < PHASE_PTS / 64; ++tile) {
            const float4 c = buf[tile * 64 + lane];
            // dot in BLAS fma-chain order; pair = ((2*dot) - sqi) - sqj, no contraction
            const float dot0 = __builtin_fmaf(a2, c.z, __builtin_fmaf(a1, c.y, __fmul_rn(a0, c.x)));
            const float p0   = __fsub_rn(__fsub_rn(__fmul_rn(2.0f, dot0), sqa), c.w);
            const float dot1 = __builtin_fmaf(b2, c.z, __builtin_fmaf(b1, c.y, __fmul_rn(b0, c.x)));
            const float p1   = __fsub_rn(__fsub_rn(__fmul_rn(2.0f, dot1), sqb), c.w);

            uint64_t m0 = __ballot(p0 < f0);
            uint64_t m1 = __ballot(p1 < f1);
            if (m0 | m1) {
                const int jbase = pbase + tile * 64;
                while (m0) {
                    const int b = __builtin_ctzll(m0);
                    m0 &= m0 - 1;
                    // scalar path: readlane -> SALU key transform
                    const unsigned pc = (unsigned)__builtin_amdgcn_readlane(__float_as_int(p0), b);
                    const unsigned tc = f2key_u(pc);
                    const unsigned jc = (unsigned)(jbase + b);
                    const uint64_t bal = __ballot(tc < T0);
                    const int pos = (int)__builtin_ctzll(bal);  // stable: after equals -> asc idx
                    const unsigned Tup = __shfl_up(T0, 1);
                    const unsigned Jup = __shfl_up(J0, 1);
                    T0 = (lane == pos) ? tc : ((lane > pos) ? Tup : T0);
                    J0 = (lane == pos) ? jc : ((lane > pos) ? Jup : J0);
                    const unsigned t16 = (unsigned)__builtin_amdgcn_readlane((int)T0, 16);
                    f0 = __uint_as_float((t16 == 0xFFFFFFFFu) ? 0x7F800000u : key2f_u(t16));
                }
                while (m1) {
                    const int b = __builtin_ctzll(m1);
                    m1 &= m1 - 1;
                    const unsigned pc = (unsigned)__builtin_amdgcn_readlane(__float_as_int(p1), b);
                    const unsigned tc = f2key_u(pc);
                    const unsigned jc = (unsigned)(jbase + b);
                    const uint64_t bal = __ballot(tc < T1);
                    const int pos = (int)__builtin_ctzll(bal);
                    const unsigned Tup = __shfl_up(T1, 1);
                    const unsigned Jup = __shfl_up(J1, 1);
                    T1 = (lane == pos) ? tc : ((lane > pos) ? Tup : T1);
                    J1 = (lane == pos) ? jc : ((lane > pos) ? Jup : J1);
                    const unsigned t16 = (unsigned)__builtin_amdgcn_readlane((int)T1, 16);
                    f1 = __uint_as_float((t16 == 0xFFFFFFFFu) ? 0x7F800000u : key2f_u(t16));
                }
            }
        }
    }

    // ranks 1..16 (rank 0 = single farthest point is dropped by the reference)
    if (lane >= 1 && lane <= KOUT) {
        out_d[q0 * KOUT + (lane - 1)] = __uint_as_float(key2f_u(T0));
        out_i[q0 * KOUT + (lane - 1)] = (float)J0;
        out_d[q1 * KOUT + (lane - 1)] = __uint_as_float(key2f_u(T1));
        out_i[q1 * KOUT + (lane - 1)] = (float)J1;
    }
}

extern "C" void kernel_launch(void* const* d_in, const int* in_sizes, int n_in,
                              void* d_out, int out_size, void* d_ws, size_t ws_size,
                              hipStream_t stream) {
    const float* x = (const float*)d_in[0];
    float* out_d = (float*)d_out;              // 8*2048*16 dists
    float* out_i = out_d + (size_t)BN * KOUT;  // 8*2048*16 indices (as float)
    const int queries_per_block = 2 * (BLOCK_THREADS / 64);
    hipLaunchKernelGGL(knn_far_kernel, dim3(BN / queries_per_block), dim3(BLOCK_THREADS),
                       PHASE_PTS * sizeof(float4), stream, x, out_d, out_i);
}